// Round 17
// baseline (249.087 us; speedup 1.0000x reference)
//
#include <hip/hip_runtime.h>
#include <hip/hip_bf16.h>
#include <cstdint>

#define N_NODES 8192
#define DDIM    64
#define DX      128
#define NEDGE   262144
#define BR      128                       // query rows per block (8 waves, 32x32 MFMA tiles)
#define BC      64                        // key/value columns per tile
#define SPLITS  8
#define TILES   (N_NODES / BC / SPLITS)   // 16 (compile-time)
#define RCAP    64                        // per-row edge bin capacity (Poisson(32), 5.7 sigma)
#define MSHIFT  66.0f                     // fixed softmax shift: scores < 64 always

typedef float f32x16 __attribute__((ext_vector_type(16)));
typedef short short8 __attribute__((ext_vector_type(8)));

__device__ __forceinline__ short f2bf(float f) {
    union { float f; uint32_t u; } v; v.f = f;
    uint32_t u = v.u;
    uint32_t r = (u + 0x7FFFu + ((u >> 16) & 1u)) >> 16;
    return (short)r;
}
__device__ __forceinline__ float bf2f(short s) {
    union { uint32_t u; float f; } v;
    v.u = ((uint32_t)(uint16_t)s) << 16;
    return v.f;
}

// ---- fused prep: [0,2048) X-build, [2048,2304) Y-transpose, [2304,3328) edges
__global__ void cpa_prep_all(const float* __restrict__ mag, const float* __restrict__ phase,
                             const int* __restrict__ ei, const float* __restrict__ ea,
                             const float* __restrict__ W, const float* __restrict__ b,
                             short* __restrict__ Xbf, short* __restrict__ Ybt,
                             float* __restrict__ es, int* __restrict__ cnt,
                             int* __restrict__ keys) {
    __shared__ short tile[64][65];
    __shared__ float wsb[5];
    const int blk = blockIdx.x;
    const int tid = threadIdx.x;
    if (blk < 2048) {
        int idx = blk * 256 + tid;                 // N*64 threads
        int i = idx >> 6, d = idx & 63;
        float m = mag[idx], p = phase[idx];
        Xbf[i * DX + d]      = f2bf(m * __cosf(p));
        Xbf[i * DX + 64 + d] = f2bf(m * __sinf(p));
    } else if (blk < 2304) {
        int bb = blk - 2048;
        int bi = bb >> 1;
        int bc = bb & 1;
        int i0 = bi * 64;
        const float* src = bc ? phase : mag;
        for (int itr = 0; itr < 16; ++itr) {
            int idx = tid + itr * 256;             // 0..4095
            int ii = idx >> 6, cc = idx & 63;
            tile[ii][cc] = f2bf(src[(size_t)(i0 + ii) * 64 + cc]);
        }
        __syncthreads();
        for (int itr = 0; itr < 16; ++itr) {
            int idx = tid + itr * 256;
            int cc = idx >> 6, ii = idx & 63;
            Ybt[(size_t)(bc * 64 + cc) * N_NODES + i0 + ii] = tile[ii][cc];
        }
    } else {
        if (tid < 64) {
            float w0 = W[tid * 4 + 0], w1 = W[tid * 4 + 1];
            float w2 = W[tid * 4 + 2], w3 = W[tid * 4 + 3];
            float bb = b[tid];
            #pragma unroll
            for (int o = 32; o > 0; o >>= 1) {
                w0 += __shfl_down(w0, o);
                w1 += __shfl_down(w1, o);
                w2 += __shfl_down(w2, o);
                w3 += __shfl_down(w3, o);
                bb += __shfl_down(bb, o);
            }
            if (tid == 0) { wsb[0] = w0; wsb[1] = w1; wsb[2] = w2; wsb[3] = w3; wsb[4] = bb; }
        }
        __syncthreads();
        int e = (blk - 2304) * 256 + tid;
        float4 a = *(const float4*)(ea + (size_t)e * 4);
        es[e] = a.x * wsb[0] + a.y * wsb[1] + a.z * wsb[2] + a.w * wsb[3] + wsb[4];
        int src = ei[e];
        int dst = ei[NEDGE + e];
        int pos = atomicAdd(&cnt[src], 1);
        if (pos < RCAP) keys[src * RCAP + pos] = (dst << 18) | e;
    }
}

// ---- per-row sort by (dst,e), mark all-but-last dup dead (numpy last-wins),
// then REPACK each slot as [31]=dead, [28:16]=dst, [15:0]=bf16(es[e]).
// All 64 slots written (pads dead) so flash needs no per-row length.
__global__ __launch_bounds__(256) void cpa_sortrows(const int* __restrict__ cnt,
                                                    const float* __restrict__ es,
                                                    int* __restrict__ keys) {
    int row  = blockIdx.x * 4 + (threadIdx.x >> 6);
    int lane = threadIdx.x & 63;
    int len  = min(cnt[row], RCAP);
    int base = row * RCAP;
    int v = (lane < len) ? keys[base + lane] : 0x7FFFFFFF;

    #pragma unroll
    for (int k = 2; k <= 64; k <<= 1) {
        #pragma unroll
        for (int j = k >> 1; j >= 1; j >>= 1) {
            int p = __shfl_xor(v, j);
            bool asc = (lane & k) == 0;
            bool low = (lane & j) == 0;
            v = (low == asc) ? min(v, p) : max(v, p);
        }
    }
    int nxt = __shfl_down(v, 1);
    bool dead = (lane + 1 < len) && ((v >> 18) == (nxt >> 18));
    int packed;
    if (lane < len) {
        int dst = (v >> 18) & 0x1FFF;
        int e   = v & 0x3FFFF;
        unsigned esb = (unsigned)(unsigned short)f2bf(es[e]);
        packed = (dst << 16) | (int)esb | (dead ? (int)0x80000000 : 0);
    } else {
        packed = (int)0x80000000;   // dead pad
    }
    keys[base + lane] = packed;
}

// ---- flash attention, 32x32x16 MFMA core (R13 structure: 512 thr, BR=128,
// SPLITS=8, 3 barriers/tile). Bias edges live in 32 REGISTERS per lane
// (lane ln holds slot ln of each of the wave's 32 rows, packed dst+bf16(es));
// per tile a branchless 32-reg window scan does rare same-wave LDS RMWs --
// zero global loads / serial chains in the bias path.
__global__ __launch_bounds__(512)
__attribute__((amdgpu_waves_per_eu(4, 4)))
void cpa_flash(
    const short* __restrict__ Xbf, const short* __restrict__ Ybt,
    const int* __restrict__ keys,
    float* __restrict__ lsplit, short* __restrict__ Opart)
{
    __shared__ short Xj[BC][136];     // X tile (j rows), stride 136
    __shared__ short Yt[DX][72];      // V tile K-transposed: Yt[feature][j-local]
    __shared__ short Pl[BR][72];      // P tile

    const int tid  = threadIdx.x;
    const int lane = tid & 63;
    const int w    = tid >> 6;        // wave 0..7
    const int l31  = lane & 31;
    const int lh   = lane >> 5;       // K-half within fragment
    const int rg   = w >> 1;          // row group (32 rows), S and PV
    const int cg   = w & 1;           // S col group / P region half
    const int ocg0 = (w & 1) * 2;     // PV col-tile pair {ocg0, ocg0+1}

    const int ib = blockIdx.x;        // 0..63
    const int split = blockIdx.y;     // 0..SPLITS-1
    const int i0 = ib * BR;
    const int jstart = split * (N_NODES / SPLITS);

    // Xi A-fragments: rows rg*32+l31, 8 K-chunks of 16 over 128 features (global, once)
    short8 afrag[8];
    #pragma unroll
    for (int kf = 0; kf < 8; ++kf)
        afrag[kf] = *(const short8*)(Xbf + (size_t)(i0 + rg * 32 + l31) * DX + kf * 16 + lh * 8);

    short8 ones;
    #pragma unroll
    for (int j = 0; j < 8; ++j) ones[j] = (short)0x3F80;   // bf16 1.0

    // bias keys for this wave's 32 rows: lane ln holds slot ln of each row
    int kreg[32];
    #pragma unroll
    for (int r = 0; r < 32; ++r)
        kreg[r] = keys[(size_t)(i0 + rg * 32 + r) * RCAP + lane];

    f32x16 O0, O1, lC;
    #pragma unroll
    for (int r = 0; r < 16; ++r) { O0[r] = 0.f; O1[r] = 0.f; lC[r] = 0.f; }

    for (int tt = 0; tt < TILES; ++tt) {
        const int j0 = jstart + tt * BC;
        // phase A: stage X_j and Y_t tiles (cooperative, vectorized)
        for (int itr = 0; itr < 2; ++itr) {
            int idx = tid + itr * 512;
            int r = idx >> 4;
            int c8 = (idx & 15) << 3;
            *(int4*)(&Xj[r][c8]) = *(const int4*)(Xbf + (size_t)(j0 + r) * DX + c8);
        }
        for (int itr = 0; itr < 2; ++itr) {
            int idx = tid + itr * 512;
            int n = idx >> 3;
            int k8 = (idx & 7) << 3;
            *(int4*)(&Yt[n][k8]) = *(const int4*)(Ybt + (size_t)n * N_NODES + j0 + k8);
        }
        __syncthreads();  // B1: staging visible

        // phase B: S (32x32) = Xi(rg) · Xj(cg)^T, 8 K-steps
        f32x16 S;
        #pragma unroll
        for (int r = 0; r < 16; ++r) S[r] = 0.f;
        #pragma unroll
        for (int kf = 0; kf < 8; ++kf) {
            short8 bfrag = *(const short8*)&Xj[cg * 32 + l31][kf * 16 + lh * 8];
            S = __builtin_amdgcn_mfma_f32_32x32x16_bf16(afrag[kf], bfrag, S, 0, 0, 0);
        }
        // p = exp(S - 66) -> own Pl region (row rg*32+rowl, col cg*32+l31)
        #pragma unroll
        for (int r = 0; r < 16; ++r) {
            int rowl = 4 * lh + (r & 3) + 8 * (r >> 2);
            Pl[rg * 32 + rowl][cg * 32 + l31] = f2bf(__expf(S[r] - MSHIFT));
        }
        // bias RMW from registers (same-wave DS ordering: own rows x own cg cols)
        {
            const int wlo = j0 + cg * 32;
            #pragma unroll
            for (int r = 0; r < 32; ++r) {
                int k = kreg[r];
                if (k >= 0) {
                    unsigned cl = (unsigned)(((k >> 16) & 0x1FFF) - wlo);
                    if (cl < 32u) {
                        short* p = &Pl[rg * 32 + r][cg * 32 + (int)cl];
                        *p = f2bf(bf2f(*p) * __expf(bf2f((short)(k & 0xFFFF))));
                    }
                }
            }
        }
        __syncthreads();  // B2: biased P visible to all waves

        // phase D: O += P·Y (2 col tiles sharing A-frags); l += P·1 (even waves)
        #pragma unroll
        for (int ks = 0; ks < 4; ++ks) {
            short8 pa  = *(const short8*)&Pl[rg * 32 + l31][ks * 16 + lh * 8];
            short8 yb0 = *(const short8*)&Yt[ocg0 * 32 + l31][ks * 16 + lh * 8];
            short8 yb1 = *(const short8*)&Yt[(ocg0 + 1) * 32 + l31][ks * 16 + lh * 8];
            O0 = __builtin_amdgcn_mfma_f32_32x32x16_bf16(pa, yb0, O0, 0, 0, 0);
            O1 = __builtin_amdgcn_mfma_f32_32x32x16_bf16(pa, yb1, O1, 0, 0, 0);
            if (!(w & 1))
                lC = __builtin_amdgcn_mfma_f32_32x32x16_bf16(pa, ones, lC, 0, 0, 0);
        }
        __syncthreads();  // B4: WAR before next staging / P-store
    }

    // epilogue: O (bf16) and l (fixed shift => merge is a plain sum)
    #pragma unroll
    for (int r = 0; r < 16; ++r) {
        int row = rg * 32 + 4 * lh + (r & 3) + 8 * (r >> 2);
        size_t base = ((size_t)split * N_NODES + i0 + row) * DX;
        Opart[base + ocg0 * 32 + l31]       = f2bf(O0[r]);
        Opart[base + (ocg0 + 1) * 32 + l31] = f2bf(O1[r]);
    }
    if (!(w & 1) && l31 == 0) {
        #pragma unroll
        for (int r = 0; r < 16; ++r) {
            int row = rg * 32 + 4 * lh + (r & 3) + 8 * (r >> 2);
            lsplit[(size_t)split * N_NODES + i0 + row] = lC[r];
        }
    }
}

// ---- merge splits (plain sums) + normalize + write [new_mag | new_phase]
__global__ void cpa_merge(const float* __restrict__ lsplit, const short* __restrict__ Opart,
                          float* __restrict__ out) {
    int gid = blockIdx.x * 256 + threadIdx.x;   // N*128 threads
    int i = gid >> 7;
    int c = gid & 127;
    float den = 0.f, num = 0.f;
    #pragma unroll
    for (int s = 0; s < SPLITS; ++s) {
        den += lsplit[(size_t)s * N_NODES + i];
        num += bf2f(Opart[((size_t)s * N_NODES + i) * DX + c]);
    }
    float val = num / den;
    if (c < 64) out[(size_t)i * 64 + c] = val;
    else        out[(size_t)N_NODES * 64 + (size_t)i * 64 + (c - 64)] = val;
}

extern "C" void kernel_launch(void* const* d_in, const int* in_sizes, int n_in,
                              void* d_out, int out_size, void* d_ws, size_t ws_size,
                              hipStream_t stream)
{
    const float* mag   = (const float*)d_in[0];
    const float* phase = (const float*)d_in[1];
    const int*   ei    = (const int*)d_in[2];     // edge_index [2][E] (int32 per harness)
    const float* ea    = (const float*)d_in[3];
    const float* W     = (const float*)d_in[4];
    const float* b     = (const float*)d_in[5];
    float* out = (float*)d_out;

    char* ws = (char*)d_ws;
    short* Xbf    = (short*)(ws + 0);               // 2 MB
    short* Ybt    = (short*)(ws + 2097152);         // 2 MB
    float* es     = (float*)(ws + 4194304);         // 1 MB
    int*   keys   = (int*)  (ws + 5242880);         // 2 MB (8192 rows x 64 bins)
    int*   cnt    = (int*)  (ws + 7340032);         // 32 KB
    float* lsplit = (float*)(ws + 7373056);         // 256 KB (8 splits)
    short* Opart  = (short*)(ws + 7635200);         // 16 MB (bf16, 8 splits)

    hipMemsetAsync(cnt, 0, N_NODES * sizeof(int), stream);
    cpa_prep_all<<<2048 + 256 + NEDGE / 256, 256, 0, stream>>>(mag, phase, ei, ea, W, b,
                                                               Xbf, Ybt, es, cnt, keys);
    cpa_sortrows<<<N_NODES / 4, 256, 0, stream>>>(cnt, es, keys);
    cpa_flash<<<dim3(N_NODES / BR, SPLITS), 512, 0, stream>>>(Xbf, Ybt, keys,
                                                              lsplit, Opart);
    cpa_merge<<<N_NODES * DX / 256, 256, 0, stream>>>(lsplit, Opart, out);
}

// Round 18
// 179.720 us; speedup vs baseline: 1.3860x; 1.3860x over previous
//
#include <hip/hip_runtime.h>
#include <hip/hip_bf16.h>
#include <hip/hip_fp16.h>
#include <cstdint>

#define N_NODES 8192
#define DDIM    64
#define DX      128
#define NEDGE   262144
#define BR      128                       // query rows per block (8 waves, 32x32 MFMA tiles)
#define BC      64                        // key/value columns per tile
#define SPLITS  8
#define TILES   (N_NODES / BC / SPLITS)   // 16 (compile-time)
#define SPLW    (N_NODES / SPLITS)        // 1024-col split window
#define RCAP    64                        // per-row edge bin capacity (Poisson(32), 5.7 sigma)
#define LCAP    32                        // per-row per-split LDS bin (Poisson(8); P(>32)~4e-13)
#define MSHIFT  66.0f                     // fixed softmax shift: scores < 64 always

typedef float f32x16 __attribute__((ext_vector_type(16)));
typedef short short8 __attribute__((ext_vector_type(8)));

__device__ __forceinline__ short f2bf(float f) {
    union { float f; uint32_t u; } v; v.f = f;
    uint32_t u = v.u;
    uint32_t r = (u + 0x7FFFu + ((u >> 16) & 1u)) >> 16;
    return (short)r;
}
__device__ __forceinline__ float bf2f(short s) {
    union { uint32_t u; float f; } v;
    v.u = ((uint32_t)(uint16_t)s) << 16;
    return v.f;
}

// ---- fused prep: [0,2048) X-build, [2048,2304) Y-transpose, [2304,3328) edges
__global__ void cpa_prep_all(const float* __restrict__ mag, const float* __restrict__ phase,
                             const int* __restrict__ ei, const float* __restrict__ ea,
                             const float* __restrict__ W, const float* __restrict__ b,
                             short* __restrict__ Xbf, short* __restrict__ Ybt,
                             float* __restrict__ es, int* __restrict__ cnt,
                             int* __restrict__ keys) {
    __shared__ short tile[64][65];
    __shared__ float wsb[5];
    const int blk = blockIdx.x;
    const int tid = threadIdx.x;
    if (blk < 2048) {
        int idx = blk * 256 + tid;                 // N*64 threads
        int i = idx >> 6, d = idx & 63;
        float m = mag[idx], p = phase[idx];
        Xbf[i * DX + d]      = f2bf(m * __cosf(p));
        Xbf[i * DX + 64 + d] = f2bf(m * __sinf(p));
    } else if (blk < 2304) {
        int bb = blk - 2048;
        int bi = bb >> 1;
        int bc = bb & 1;
        int i0 = bi * 64;
        const float* src = bc ? phase : mag;
        for (int itr = 0; itr < 16; ++itr) {
            int idx = tid + itr * 256;             // 0..4095
            int ii = idx >> 6, cc = idx & 63;
            tile[ii][cc] = f2bf(src[(size_t)(i0 + ii) * 64 + cc]);
        }
        __syncthreads();
        for (int itr = 0; itr < 16; ++itr) {
            int idx = tid + itr * 256;
            int cc = idx >> 6, ii = idx & 63;
            Ybt[(size_t)(bc * 64 + cc) * N_NODES + i0 + ii] = tile[ii][cc];
        }
    } else {
        if (tid < 64) {
            float w0 = W[tid * 4 + 0], w1 = W[tid * 4 + 1];
            float w2 = W[tid * 4 + 2], w3 = W[tid * 4 + 3];
            float bb = b[tid];
            #pragma unroll
            for (int o = 32; o > 0; o >>= 1) {
                w0 += __shfl_down(w0, o);
                w1 += __shfl_down(w1, o);
                w2 += __shfl_down(w2, o);
                w3 += __shfl_down(w3, o);
                bb += __shfl_down(bb, o);
            }
            if (tid == 0) { wsb[0] = w0; wsb[1] = w1; wsb[2] = w2; wsb[3] = w3; wsb[4] = bb; }
        }
        __syncthreads();
        int e = (blk - 2304) * 256 + tid;
        float4 a = *(const float4*)(ea + (size_t)e * 4);
        es[e] = a.x * wsb[0] + a.y * wsb[1] + a.z * wsb[2] + a.w * wsb[3] + wsb[4];
        int src = ei[e];
        int dst = ei[NEDGE + e];
        int pos = atomicAdd(&cnt[src], 1);
        if (pos < RCAP) keys[src * RCAP + pos] = (dst << 18) | e;   // raw: dst | edge id
    }
}

// ---- flash attention, 32x32x16 MFMA core (R13 structure: 512 thr, BR=128,
// SPLITS=8, 3 barriers/tile). Bias edges are filtered ONCE per block into LDS
// bins (per-row, this split's window only), deduped by max-e (exact numpy
// last-wins, order-independent), es packed as f16. Per tile the bias phase is
// ~8 independent LDS loads per row -- no global latency, no serial chain.
// No sort kernel needed at all. All extra state in LDS (64-VGPR budget holds).
__global__ __launch_bounds__(512, 4) void cpa_flash(
    const short* __restrict__ Xbf, const short* __restrict__ Ybt,
    const float* __restrict__ es, const int* __restrict__ keys,
    const int* __restrict__ cnt,
    float* __restrict__ lsplit, short* __restrict__ Opart)
{
    __shared__ short Xj[BC][136];     // 17408 B
    __shared__ short Yt[DX][72];      // 18432 B
    __shared__ short Pl[BR][72];      // 18432 B
    __shared__ int   lkeys[BR][LCAP]; // 16384 B  (filtered bias edges, this split)
    __shared__ int   lcnt[BR];        //   512 B  -> total 71168 B, 2 blocks/CU

    const int tid  = threadIdx.x;
    const int lane = tid & 63;
    const int w    = tid >> 6;        // wave 0..7
    const int l31  = lane & 31;
    const int lh   = lane >> 5;       // K-half within fragment
    const int rg   = w >> 1;          // row group (32 rows), S and PV
    const int cg   = w & 1;           // S col group / P region half
    const int ocg0 = (w & 1) * 2;     // PV col-tile pair {ocg0, ocg0+1}

    const int ib = blockIdx.x;        // 0..63
    const int split = blockIdx.y;     // 0..SPLITS-1
    const int i0 = ib * BR;
    const int jstart = split * SPLW;

    // Xi A-fragments: rows rg*32+l31, 8 K-chunks of 16 over 128 features (global, once)
    short8 afrag[8];
    #pragma unroll
    for (int kf = 0; kf < 8; ++kf)
        afrag[kf] = *(const short8*)(Xbf + (size_t)(i0 + rg * 32 + l31) * DX + kf * 16 + lh * 8);

    short8 ones;
    #pragma unroll
    for (int j = 0; j < 8; ++j) ones[j] = (short)0x3F80;   // bf16 1.0

    // ---- preamble: filter this split's bias edges into LDS bins ----
    if (tid < BR) lcnt[tid] = 0;
    __syncthreads();
    #pragma unroll
    for (int k = 0; k < 16; ++k) {
        int idx = tid + k * 512;                   // 0..8191 (coalesced in slot)
        int r = idx >> 6, s = idx & 63;
        int i = i0 + r;
        if (s < min(cnt[i], RCAP)) {
            int v = keys[(size_t)i * RCAP + s];
            int dst = (v >> 18) & 0x1FFF;
            unsigned drel = (unsigned)(dst - jstart);
            if (drel < (unsigned)SPLW) {
                int pos = atomicAdd(&lcnt[r], 1);
                if (pos < LCAP) lkeys[r][pos] = ((int)drel << 18) | (v & 0x3FFFF);
            }
        }
    }
    __syncthreads();
    // dedup (max-e wins, exact) + convert to [25:16]=dst_rel, [15:0]=f16(es)
    if (cg == 0 && lane < 32) {
        int r = rg * 32 + l31;
        int n = min(lcnt[r], LCAP);
        lcnt[r] = n;
        unsigned deadmask = 0;
        for (int i2 = 0; i2 < n; ++i2) {
            int vi = lkeys[r][i2];
            int di = vi >> 18, ei = vi & 0x3FFFF;
            for (int j2 = 0; j2 < n; ++j2) {
                int vj = lkeys[r][j2];
                if ((vj >> 18) == di && (vj & 0x3FFFF) > ei) { deadmask |= 1u << i2; break; }
            }
        }
        for (int i2 = 0; i2 < n; ++i2) {
            int vi = lkeys[r][i2];
            if (deadmask & (1u << i2)) {
                lkeys[r][i2] = (int)0x80000000;
            } else {
                union { __half h; unsigned short u; } cv;
                cv.h = __float2half(es[vi & 0x3FFFF]);
                lkeys[r][i2] = ((vi >> 18) << 16) | (int)cv.u;
            }
        }
    }
    __syncthreads();

    f32x16 O0, O1, lC;
    #pragma unroll
    for (int r = 0; r < 16; ++r) { O0[r] = 0.f; O1[r] = 0.f; lC[r] = 0.f; }

    for (int tt = 0; tt < TILES; ++tt) {
        const int j0 = jstart + tt * BC;
        // phase A: stage X_j and Y_t tiles (cooperative, vectorized)
        for (int itr = 0; itr < 2; ++itr) {
            int idx = tid + itr * 512;
            int r = idx >> 4;
            int c8 = (idx & 15) << 3;
            *(int4*)(&Xj[r][c8]) = *(const int4*)(Xbf + (size_t)(j0 + r) * DX + c8);
        }
        for (int itr = 0; itr < 2; ++itr) {
            int idx = tid + itr * 512;
            int n = idx >> 3;
            int k8 = (idx & 7) << 3;
            *(int4*)(&Yt[n][k8]) = *(const int4*)(Ybt + (size_t)n * N_NODES + j0 + k8);
        }
        __syncthreads();  // B1: staging visible

        // phase B: S (32x32) = Xi(rg) · Xj(cg)^T, 8 K-steps
        f32x16 S;
        #pragma unroll
        for (int r = 0; r < 16; ++r) S[r] = 0.f;
        #pragma unroll
        for (int kf = 0; kf < 8; ++kf) {
            short8 bfrag = *(const short8*)&Xj[cg * 32 + l31][kf * 16 + lh * 8];
            S = __builtin_amdgcn_mfma_f32_32x32x16_bf16(afrag[kf], bfrag, S, 0, 0, 0);
        }
        // p = exp(S - 66) -> own Pl region (row rg*32+rowl, col cg*32+l31)
        #pragma unroll
        for (int r = 0; r < 16; ++r) {
            int rowl = 4 * lh + (r & 3) + 8 * (r >> 2);
            Pl[rg * 32 + rowl][cg * 32 + l31] = f2bf(__expf(S[r] - MSHIFT));
        }
        // bias RMW from LDS bins (same-wave DS ordering: own rows x own cg cols)
        if (lane < 32) {
            int r = rg * 32 + l31;
            const int tlo = tt * BC + cg * 32;     // dst_rel window low
            int n = lcnt[r];
            for (int j2 = 0; j2 < n; ++j2) {
                int k = lkeys[r][j2];
                if (k >= 0) {
                    unsigned cl = (unsigned)((k >> 16) - tlo);
                    if (cl < 32u) {
                        union { __half h; unsigned short u; } cv;
                        cv.u = (unsigned short)(k & 0xFFFF);
                        short* p = &Pl[r][cg * 32 + (int)cl];
                        *p = f2bf(bf2f(*p) * __expf(__half2float(cv.h)));
                    }
                }
            }
        }
        __syncthreads();  // B2: biased P visible to all waves

        // phase D: O += P·Y (2 col tiles sharing A-frags); l += P·1 (even waves)
        #pragma unroll
        for (int ks = 0; ks < 4; ++ks) {
            short8 pa  = *(const short8*)&Pl[rg * 32 + l31][ks * 16 + lh * 8];
            short8 yb0 = *(const short8*)&Yt[ocg0 * 32 + l31][ks * 16 + lh * 8];
            short8 yb1 = *(const short8*)&Yt[(ocg0 + 1) * 32 + l31][ks * 16 + lh * 8];
            O0 = __builtin_amdgcn_mfma_f32_32x32x16_bf16(pa, yb0, O0, 0, 0, 0);
            O1 = __builtin_amdgcn_mfma_f32_32x32x16_bf16(pa, yb1, O1, 0, 0, 0);
            if (!(w & 1))
                lC = __builtin_amdgcn_mfma_f32_32x32x16_bf16(pa, ones, lC, 0, 0, 0);
        }
        __syncthreads();  // B4: WAR before next staging / P-store
    }

    // epilogue: O (bf16) and l (fixed shift => merge is a plain sum)
    #pragma unroll
    for (int r = 0; r < 16; ++r) {
        int row = rg * 32 + 4 * lh + (r & 3) + 8 * (r >> 2);
        size_t base = ((size_t)split * N_NODES + i0 + row) * DX;
        Opart[base + ocg0 * 32 + l31]       = f2bf(O0[r]);
        Opart[base + (ocg0 + 1) * 32 + l31] = f2bf(O1[r]);
    }
    if (!(w & 1) && l31 == 0) {
        #pragma unroll
        for (int r = 0; r < 16; ++r) {
            int row = rg * 32 + 4 * lh + (r & 3) + 8 * (r >> 2);
            lsplit[(size_t)split * N_NODES + i0 + row] = lC[r];
        }
    }
}

// ---- merge splits (plain sums) + normalize + write [new_mag | new_phase]
__global__ void cpa_merge(const float* __restrict__ lsplit, const short* __restrict__ Opart,
                          float* __restrict__ out) {
    int gid = blockIdx.x * 256 + threadIdx.x;   // N*128 threads
    int i = gid >> 7;
    int c = gid & 127;
    float den = 0.f, num = 0.f;
    #pragma unroll
    for (int s = 0; s < SPLITS; ++s) {
        den += lsplit[(size_t)s * N_NODES + i];
        num += bf2f(Opart[((size_t)s * N_NODES + i) * DX + c]);
    }
    float val = num / den;
    if (c < 64) out[(size_t)i * 64 + c] = val;
    else        out[(size_t)N_NODES * 64 + (size_t)i * 64 + (c - 64)] = val;
}

extern "C" void kernel_launch(void* const* d_in, const int* in_sizes, int n_in,
                              void* d_out, int out_size, void* d_ws, size_t ws_size,
                              hipStream_t stream)
{
    const float* mag   = (const float*)d_in[0];
    const float* phase = (const float*)d_in[1];
    const int*   ei    = (const int*)d_in[2];     // edge_index [2][E] (int32 per harness)
    const float* ea    = (const float*)d_in[3];
    const float* W     = (const float*)d_in[4];
    const float* b     = (const float*)d_in[5];
    float* out = (float*)d_out;

    char* ws = (char*)d_ws;
    short* Xbf    = (short*)(ws + 0);               // 2 MB
    short* Ybt    = (short*)(ws + 2097152);         // 2 MB
    float* es     = (float*)(ws + 4194304);         // 1 MB
    int*   keys   = (int*)  (ws + 5242880);         // 2 MB (8192 rows x 64 bins, raw)
    int*   cnt    = (int*)  (ws + 7340032);         // 32 KB
    float* lsplit = (float*)(ws + 7373056);         // 256 KB (8 splits)
    short* Opart  = (short*)(ws + 7635200);         // 16 MB (bf16, 8 splits)

    hipMemsetAsync(cnt, 0, N_NODES * sizeof(int), stream);
    cpa_prep_all<<<2048 + 256 + NEDGE / 256, 256, 0, stream>>>(mag, phase, ei, ea, W, b,
                                                               Xbf, Ybt, es, cnt, keys);
    cpa_flash<<<dim3(N_NODES / BR, SPLITS), 512, 0, stream>>>(Xbf, Ybt, es, keys, cnt,
                                                              lsplit, Opart);
    cpa_merge<<<N_NODES * DX / 256, 256, 0, stream>>>(lsplit, Opart, out);
}